// Round 7
// baseline (574.301 us; speedup 1.0000x reference)
//
#include <hip/hip_runtime.h>
#include <hip/hip_bf16.h>

#define B_   16
#define NH   12
#define NTOK 576
#define HD   64
#define CH   768
#define NELEM (B_*NH*NTOK*HD)   // 7,077,888 floats per q/k/v buffer
#define VT8SZ (NTOK*HD)         // 36864 B per bh (int8 transposed V)
#define FIXCAP 16384
#define VPAD 176

typedef short v8s __attribute__((ext_vector_type(8)));
typedef short v4s __attribute__((ext_vector_type(4)));
typedef float v4f __attribute__((ext_vector_type(4)));
typedef int   v4i __attribute__((ext_vector_type(4)));

// split 4 fp32 into hi/lo bf16 (RN): f = hi + lo + O(2^-18 |f|)
static __device__ __forceinline__ void split4(const float* f, v4s& hi, v4s& lo)
{
    #pragma unroll
    for (int i = 0; i < 4; ++i) {
        __hip_bfloat16 h = __float2bfloat16(f[i]);
        float hf = __bfloat162float(h);
        __hip_bfloat16 l = __float2bfloat16(f[i] - hf);
        hi[i] = __builtin_bit_cast(short, h);
        lo[i] = __builtin_bit_cast(short, l);
    }
}

// ---------------------------------------------------------------------------
// K1: qkv[b,n,j] = sum_c x[b,c,n] * w_qkv[j,c]  via 3-term split-bf16 MFMA.
// (unchanged from round-6 passing version, plus fixn_g zeroing by one thread)
// ---------------------------------------------------------------------------
__global__ __launch_bounds__(256) void qkv_mfma(const float* __restrict__ x,
    const float* __restrict__ w, float* __restrict__ q, float* __restrict__ k,
    float* __restrict__ v, int* __restrict__ fixn_g)
{
    if (blockIdx.x == 0 && threadIdx.x == 0) *fixn_g = 0;

    __shared__ short Ah[64*40], Al[64*40];
    __shared__ short Bh[256*40], Bl[256*40];
    const int tid = threadIdx.x;
    int g = blockIdx.x;
    g = (g & 7) * 162 + (g >> 3);        // bijective: 1296 = 8*162
    const int b  = g / 81;
    const int rr = g % 81;
    const int jb = rr / 9;
    const int mb = rr % 9;
    const int n0 = mb * 64;
    const int j0 = jb * 256;
    const int lane = tid & 63, wv = tid >> 6;

    const int cq  = tid & 7;
    const int rw0 = tid >> 3;

    const float* xb  = x + (size_t)b * CH * NTOK + n0;
    const float* wbp = w + (size_t)j0 * CH;

    float areg[2][4];
    float breg[8][4];

    #pragma unroll
    for (int s = 0; s < 2; ++s) {
        const int nl = rw0 + 32*s;
        #pragma unroll
        for (int i = 0; i < 4; ++i)
            areg[s][i] = xb[(size_t)(cq*4 + i) * NTOK + nl];
    }
    #pragma unroll
    for (int s = 0; s < 8; ++s) {
        const int jl = rw0 + 32*s;
        const float4 t = *(const float4*)(wbp + (size_t)jl * CH + cq*4);
        breg[s][0]=t.x; breg[s][1]=t.y; breg[s][2]=t.z; breg[s][3]=t.w;
    }

    v4f acc[4][4];
    #pragma unroll
    for (int a = 0; a < 4; ++a)
        #pragma unroll
        for (int c = 0; c < 4; ++c) acc[a][c] = (v4f){0.f,0.f,0.f,0.f};

    for (int it = 0; it < 24; ++it) {
        __syncthreads();
        #pragma unroll
        for (int s = 0; s < 2; ++s) {
            v4s hi, lo; split4(areg[s], hi, lo);
            const int nl = rw0 + 32*s;
            *(v4s*)&Ah[nl*40 + cq*4] = hi;
            *(v4s*)&Al[nl*40 + cq*4] = lo;
        }
        #pragma unroll
        for (int s = 0; s < 8; ++s) {
            v4s hi, lo; split4(breg[s], hi, lo);
            const int jl = rw0 + 32*s;
            *(v4s*)&Bh[jl*40 + cq*4] = hi;
            *(v4s*)&Bl[jl*40 + cq*4] = lo;
        }
        __syncthreads();
        if (it < 23) {
            const int c0 = (it + 1) * 32;
            #pragma unroll
            for (int s = 0; s < 2; ++s) {
                const int nl = rw0 + 32*s;
                #pragma unroll
                for (int i = 0; i < 4; ++i)
                    areg[s][i] = xb[(size_t)(c0 + cq*4 + i) * NTOK + nl];
            }
            #pragma unroll
            for (int s = 0; s < 8; ++s) {
                const int jl = rw0 + 32*s;
                const float4 t = *(const float4*)(wbp + (size_t)jl * CH + c0 + cq*4);
                breg[s][0]=t.x; breg[s][1]=t.y; breg[s][2]=t.z; breg[s][3]=t.w;
            }
        }
        const int krow = lane & 15;
        const int k0   = (lane >> 4) * 8;
        v8s ah[4], al2[4], bh[4], bl[4];
        #pragma unroll
        for (int mt = 0; mt < 4; ++mt) {
            ah[mt]  = *(v8s*)&Ah[(mt*16 + krow)*40 + k0];
            al2[mt] = *(v8s*)&Al[(mt*16 + krow)*40 + k0];
        }
        #pragma unroll
        for (int jt = 0; jt < 4; ++jt) {
            bh[jt] = *(v8s*)&Bh[(wv*64 + jt*16 + krow)*40 + k0];
            bl[jt] = *(v8s*)&Bl[(wv*64 + jt*16 + krow)*40 + k0];
        }
        #pragma unroll
        for (int mt = 0; mt < 4; ++mt)
            #pragma unroll
            for (int jt = 0; jt < 4; ++jt) {
                acc[mt][jt] = __builtin_amdgcn_mfma_f32_16x16x32_bf16(ah[mt],  bh[jt], acc[mt][jt], 0, 0, 0);
                acc[mt][jt] = __builtin_amdgcn_mfma_f32_16x16x32_bf16(ah[mt],  bl[jt], acc[mt][jt], 0, 0, 0);
                acc[mt][jt] = __builtin_amdgcn_mfma_f32_16x16x32_bf16(al2[mt], bh[jt], acc[mt][jt], 0, 0, 0);
            }
    }

    const int sec = jb / 3;
    float* dst = (sec == 0) ? q : (sec == 1) ? k : v;
    const int h    = (jb % 3) * 4 + wv;
    const int col  = lane & 15;
    const int row4 = (lane >> 4) * 4;
    #pragma unroll
    for (int mt = 0; mt < 4; ++mt)
        #pragma unroll
        for (int jt = 0; jt < 4; ++jt) {
            const int dd = jt*16 + col;
            float* o = dst + (((size_t)b*NH + h)*NTOK + n0 + mt*16 + row4) * HD + dd;
            #pragma unroll
            for (int rg = 0; rg < 4; ++rg)
                o[(size_t)rg * HD] = acc[mt][jt][rg];
        }
}

// ---------------------------------------------------------------------------
// K2a: one pass over q,k,v per (bh, 144-row chunk): ballot sign masks,
// |q|/|k| partial sums, per-column |v| max partials, borderline queue.
// Grid (192, 4) x 256 threads.
// ---------------------------------------------------------------------------
__global__ __launch_bounds__(256) void reduce_pass(
    const float* __restrict__ q, const float* __restrict__ k,
    const float* __restrict__ v,
    unsigned long long* __restrict__ qm, unsigned long long* __restrict__ km,
    float* __restrict__ sumq_p, float* __restrict__ sumk_p,
    float* __restrict__ vmax_p, int* __restrict__ fixq_g,
    int* __restrict__ fixn_g)
{
    const int bh = blockIdx.x, ch = blockIdx.y;
    const int tid = threadIdx.x, lane = tid & 63, wv = tid >> 6;
    const size_t base = (size_t)bh * (NTOK * HD);
    const float* qb = q + base;
    const float* kb = k + base;
    const float* vb = v + base;
    const int n0 = ch * 144;

    float sq = 0.f, sk = 0.f, vmx = 0.f;
    for (int n = n0 + wv; n < n0 + 144; n += 4) {
        const float qv = qb[n*HD + lane];
        const float kv = kb[n*HD + lane];
        const float vv = vb[n*HD + lane];
        sq += fabsf(qv); sk += fabsf(kv); vmx = fmaxf(vmx, fabsf(vv));
        const unsigned long long mq = __ballot(qv >= 0.f);
        const unsigned long long mk = __ballot(kv >= 0.f);
        if (lane == 0) {
            qm[(size_t)bh*NTOK + n] = mq;
            km[(size_t)bh*NTOK + n] = mk;
        }
        if (fabsf(qv) < 1e-4f) {
            int s_ = atomicAdd(fixn_g, 1);
            if (s_ < FIXCAP) fixq_g[s_] = bh | (n << 8) | (lane << 18);
        }
        if (fabsf(kv) < 1e-4f) {
            int s_ = atomicAdd(fixn_g, 1);
            if (s_ < FIXCAP) fixq_g[s_] = bh | (n << 8) | (lane << 18) | (1 << 24);
        }
    }

    __shared__ float r1[256], r2[256], vm[256];
    r1[tid] = sq; r2[tid] = sk; vm[tid] = vmx;
    __syncthreads();
    for (int s = 128; s > 0; s >>= 1) {
        if (tid < s) { r1[tid] += r1[tid + s]; r2[tid] += r2[tid + s]; }
        __syncthreads();
    }
    if (tid == 0) { sumq_p[bh*4 + ch] = r1[0]; sumk_p[bh*4 + ch] = r2[0]; }
    if (tid < 64)
        vmax_p[((size_t)bh*4 + ch)*64 + tid] =
            fmaxf(fmaxf(vm[tid], vm[tid+64]), fmaxf(vm[tid+128], vm[tid+192]));
}

// ---------------------------------------------------------------------------
// K2b: finalize cs, svs, scale from partials. Grid 192 x 64 threads.
// ---------------------------------------------------------------------------
__global__ __launch_bounds__(64) void finalize(
    const float* __restrict__ sumq_p, const float* __restrict__ sumk_p,
    const float* __restrict__ vmax_p, float* __restrict__ cs,
    float* __restrict__ svs_g, float* __restrict__ scale_g)
{
    const int bh = blockIdx.x, d = threadIdx.x;
    if (d == 0) {
        const float msq = (sumq_p[bh*4] + sumq_p[bh*4+1] + sumq_p[bh*4+2] +
                           sumq_p[bh*4+3]) * (1.f / (NTOK * HD));
        const float msk = (sumk_p[bh*4] + sumk_p[bh*4+1] + sumk_p[bh*4+2] +
                           sumk_p[bh*4+3]) * (1.f / (NTOK * HD));
        cs[bh] = msq * msk * 0.125f;
    }
    const float mm = fmaxf(
        fmaxf(vmax_p[((size_t)bh*4+0)*64 + d], vmax_p[((size_t)bh*4+1)*64 + d]),
        fmaxf(vmax_p[((size_t)bh*4+2)*64 + d], vmax_p[((size_t)bh*4+3)*64 + d]));
    const float svs = 127.f / (mm + 1e-6f);
    svs_g[bh*64 + d] = svs;
    scale_g[bh*64 + d] = (1.f/255.f) / (svs + 1e-6f);
}

// ---------------------------------------------------------------------------
// K2c: v -> int8 transposed [d][576] (via LDS), colsum partials.
// Grid (192, 4) x 256 threads.
// ---------------------------------------------------------------------------
__global__ __launch_bounds__(256) void vquant(const float* __restrict__ v,
    const float* __restrict__ svs_g, unsigned char* __restrict__ vt8,
    int* __restrict__ csum_p)
{
    const int bh = blockIdx.x, ch = blockIdx.y;
    const int tid = threadIdx.x, d = tid & 63;
    const float* vb = v + (size_t)bh * NTOK * HD + ch * 144 * HD;
    __shared__ unsigned char vt[64 * VPAD];
    __shared__ int cs_l[256];
    const float s = svs_g[bh*64 + d];
    int part = 0;
    for (int i = tid; i < 144 * 64; i += 256) {
        const int nl = i >> 6;
        const int iq = (int)rintf(vb[i] * s);       // in [-127,127]
        part += iq;
        vt[d*VPAD + nl] = (unsigned char)(iq & 255);
    }
    cs_l[tid] = part;
    __syncthreads();
    if (tid < 64)
        csum_p[((size_t)bh*4 + ch)*64 + tid] =
            cs_l[tid] + cs_l[tid+64] + cs_l[tid+128] + cs_l[tid+192];
    unsigned char* dst = vt8 + (size_t)bh * VT8SZ + ch * 144;
    for (int idx = tid; idx < 576; idx += 256) {
        const int row = idx / 9, seg = idx % 9;
        *(int4*)(dst + row*576 + seg*16) = *(const int4*)&vt[row*VPAD + seg*16];
    }
}

// ---------------------------------------------------------------------------
// K2d: borderline sign fixup — strict sequential fp32 fmaf chain over c
// (bit-identical order to round-3/5/6), grid-stride over global queue.
// ---------------------------------------------------------------------------
__global__ __launch_bounds__(256) void fixup(const float* __restrict__ x,
    const float* __restrict__ wqkv, unsigned long long* __restrict__ qm,
    unsigned long long* __restrict__ km, const int* __restrict__ fixq_g,
    const int* __restrict__ fixn_g)
{
    const int total = min(*fixn_g, FIXCAP);
    for (int e = blockIdx.x*256 + threadIdx.x; e < total; e += gridDim.x*256) {
        const int rec = fixq_g[e];
        const int bh  = rec & 255;
        const int n   = (rec >> 8) & 1023;
        const int dd  = (rec >> 18) & 63;
        const int isk = (rec >> 24) & 1;
        const int b = bh / NH, h = bh % NH;
        const float* wr = wqkv + (size_t)(isk*CH + h*HD + dd) * CH;
        const float* xr = x + (size_t)b * CH * NTOK + n;
        float s = 0.f;
        #pragma unroll 8
        for (int c = 0; c < CH; ++c)
            s = fmaf(xr[(size_t)c * NTOK], wr[c], s);
        unsigned* a32 = (unsigned*)((isk ? km : qm) + (size_t)bh*NTOK + n);
        const unsigned bit = 1u << (dd & 31);
        if (s >= 0.f) atomicOr(&a32[dd >> 5], bit);
        else          atomicAnd(&a32[dd >> 5], ~bit);
    }
}

// ---------------------------------------------------------------------------
// K3: fused binary attention via exact int8 MFMA PV + 65-entry exp table.
// (round-6 passing version; colsum now summed from 4 partials)
// ---------------------------------------------------------------------------
__global__ __launch_bounds__(256) void attn_i8(
    const unsigned long long* __restrict__ qm,
    const unsigned long long* __restrict__ km,
    const unsigned char* __restrict__ vt8, const float* __restrict__ cs,
    const int* __restrict__ csum_p, const float* __restrict__ scale_g,
    float* __restrict__ pre)
{
    const int tid = threadIdx.x;
    const int t0 = blockIdx.x << 6;
    const int h  = blockIdx.y;
    const int b  = blockIdx.z;
    const int bh = b * NH + h;

    __shared__ unsigned long long kml[NTOK];
    __shared__ unsigned long long qml[64];
    __shared__ float rs[64];
    __shared__ float table[65];
    __shared__ unsigned char vt[64*592];

    for (int i = tid; i < NTOK; i += 256) kml[i] = km[(size_t)bh * NTOK + i];
    if (tid < 64) qml[tid] = qm[(size_t)bh * NTOK + t0 + tid];
    const float c = cs[bh];
    if (tid < 65) table[tid] = __expf(c * (float)(64 - 2 * tid));
    {
        const unsigned char* src = vt8 + (size_t)bh * VT8SZ;
        #pragma unroll
        for (int t = 0; t < 9; ++t) {
            const int idx = tid + t*256;
            const int row = idx / 36, seg = idx % 36;
            *(int4*)&vt[row*592 + seg*16] = *(const int4*)(src + row*576 + seg*16);
        }
    }
    __syncthreads();

    const int wv = tid >> 6, lane = tid & 63;
    for (int r = wv; r < 64; r += 4) {
        const unsigned long long qq = qml[r];
        float s = 0.f;
        for (int m = lane; m < NTOK; m += 64) {
            const int pc = __popcll(qq ^ kml[m]);
            s += table[pc];
        }
        #pragma unroll
        for (int off = 32; off; off >>= 1) s += __shfl_xor(s, off, 64);
        if (lane == 0) rs[r] = 1.f / s;
    }
    __syncthreads();

    const int row_l = lane & 15;
    const int kgrp  = lane >> 4;
    const unsigned long long uq = qml[wv*16 + row_l];
    const float rsr = rs[wv*16 + row_l];
    v4i acc[4];
    #pragma unroll
    for (int jt = 0; jt < 4; ++jt) acc[jt] = (v4i){0,0,0,0};

    for (int ch = 0; ch < 9; ++ch) {
        const int mb = ch*64 + kgrp*16;
        int wds[4];
        #pragma unroll
        for (int wq = 0; wq < 4; ++wq) {
            int pk = 0;
            #pragma unroll
            for (int j = 0; j < 4; ++j) {
                const int pc = __popcll(uq ^ kml[mb + wq*4 + j]);
                const float p = table[pc] * rsr;
                const int iq = (int)rintf(p * 255.f) - 128;
                pk |= (iq & 255) << (8*j);
            }
            wds[wq] = pk;
        }
        v4i a; a[0]=wds[0]; a[1]=wds[1]; a[2]=wds[2]; a[3]=wds[3];
        #pragma unroll
        for (int jt = 0; jt < 4; ++jt) {
            const v4i bfr = *(const v4i*)&vt[(jt*16 + row_l)*592 + mb];
            acc[jt] = __builtin_amdgcn_mfma_i32_16x16x64_i8(a, bfr, acc[jt], 0, 0, 0);
        }
    }

    const int rb = kgrp * 4;
    #pragma unroll
    for (int jt = 0; jt < 4; ++jt) {
        const int dd = jt*16 + row_l;
        const int csd = csum_p[((size_t)bh*4+0)*64 + dd] +
                        csum_p[((size_t)bh*4+1)*64 + dd] +
                        csum_p[((size_t)bh*4+2)*64 + dd] +
                        csum_p[((size_t)bh*4+3)*64 + dd];
        const float scd = scale_g[bh*64 + dd];
        #pragma unroll
        for (int rg = 0; rg < 4; ++rg) {
            const int n = t0 + wv*16 + rb + rg;
            pre[((size_t)b * NTOK + n) * CH + h * HD + dd] =
                (float)(acc[jt][rg] + 128 * csd) * scd;
        }
    }
}

// ---------------------------------------------------------------------------
// K4: out[b,co,n] = sum_j pre[b,n,j]*w_proj[co,j] + bias[co], split-bf16 MFMA.
// (unchanged from round-6 passing version)
// ---------------------------------------------------------------------------
__global__ __launch_bounds__(256) void proj_mfma(const float* __restrict__ pre,
    const float* __restrict__ w, const float* __restrict__ bias,
    float* __restrict__ out)
{
    __shared__ short Awh[256*40], Awl[256*40];
    __shared__ short Bph[64*40],  Bpl[64*40];
    const int tid = threadIdx.x;
    int g = blockIdx.x;
    g = (g & 7) * 54 + (g >> 3);         // bijective: 432 = 8*54
    const int b  = g / 27;
    const int rr = g % 27;
    const int cb = rr / 9;
    const int nb = rr % 9;
    const int co0 = cb * 256;
    const int nn0 = nb * 64;
    const int lane = tid & 63, wv = tid >> 6;
    const int cq  = tid & 7;
    const int rw0 = tid >> 3;

    const float* wp = w + (size_t)co0 * CH;
    const float* pb = pre + ((size_t)b * NTOK + nn0) * CH;

    float areg[8][4];
    float breg[2][4];

    #pragma unroll
    for (int s = 0; s < 8; ++s) {
        const int cl = rw0 + 32*s;
        const float4 t = *(const float4*)(wp + (size_t)cl * CH + cq*4);
        areg[s][0]=t.x; areg[s][1]=t.y; areg[s][2]=t.z; areg[s][3]=t.w;
    }
    #pragma unroll
    for (int s = 0; s < 2; ++s) {
        const int nl = rw0 + 32*s;
        const float4 t = *(const float4*)(pb + (size_t)nl * CH + cq*4);
        breg[s][0]=t.x; breg[s][1]=t.y; breg[s][2]=t.z; breg[s][3]=t.w;
    }

    v4f acc[4][4];
    #pragma unroll
    for (int a = 0; a < 4; ++a)
        #pragma unroll
        for (int c = 0; c < 4; ++c) acc[a][c] = (v4f){0.f,0.f,0.f,0.f};

    for (int it = 0; it < 24; ++it) {
        __syncthreads();
        #pragma unroll
        for (int s = 0; s < 8; ++s) {
            v4s hi, lo; split4(areg[s], hi, lo);
            const int cl = rw0 + 32*s;
            *(v4s*)&Awh[cl*40 + cq*4] = hi;
            *(v4s*)&Awl[cl*40 + cq*4] = lo;
        }
        #pragma unroll
        for (int s = 0; s < 2; ++s) {
            v4s hi, lo; split4(breg[s], hi, lo);
            const int nl = rw0 + 32*s;
            *(v4s*)&Bph[nl*40 + cq*4] = hi;
            *(v4s*)&Bpl[nl*40 + cq*4] = lo;
        }
        __syncthreads();
        if (it < 23) {
            const int k0g = (it + 1) * 32;
            #pragma unroll
            for (int s = 0; s < 8; ++s) {
                const int cl = rw0 + 32*s;
                const float4 t = *(const float4*)(wp + (size_t)cl * CH + k0g + cq*4);
                areg[s][0]=t.x; areg[s][1]=t.y; areg[s][2]=t.z; areg[s][3]=t.w;
            }
            #pragma unroll
            for (int s = 0; s < 2; ++s) {
                const int nl = rw0 + 32*s;
                const float4 t = *(const float4*)(pb + (size_t)nl * CH + k0g + cq*4);
                breg[s][0]=t.x; breg[s][1]=t.y; breg[s][2]=t.z; breg[s][3]=t.w;
            }
        }
        const int krow = lane & 15;
        const int k0   = (lane >> 4) * 8;
        v8s ah[4], al2[4], bh[4], bl[4];
        #pragma unroll
        for (int mt = 0; mt < 4; ++mt) {
            ah[mt]  = *(v8s*)&Awh[(wv*64 + mt*16 + krow)*40 + k0];
            al2[mt] = *(v8s*)&Awl[(wv*64 + mt*16 + krow)*40 + k0];
        }
        #pragma unroll
        for (int jt = 0; jt < 4; ++jt) {
            bh[jt] = *(v8s*)&Bph[(jt*16 + krow)*40 + k0];
            bl[jt] = *(v8s*)&Bpl[(jt*16 + krow)*40 + k0];
        }
        #pragma unroll
        for (int mt = 0; mt < 4; ++mt)
            #pragma unroll
            for (int jt = 0; jt < 4; ++jt) {
                acc[mt][jt] = __builtin_amdgcn_mfma_f32_16x16x32_bf16(ah[mt],  bh[jt], acc[mt][jt], 0, 0, 0);
                acc[mt][jt] = __builtin_amdgcn_mfma_f32_16x16x32_bf16(ah[mt],  bl[jt], acc[mt][jt], 0, 0, 0);
                acc[mt][jt] = __builtin_amdgcn_mfma_f32_16x16x32_bf16(al2[mt], bh[jt], acc[mt][jt], 0, 0, 0);
            }
    }

    const int col  = lane & 15;
    const int row4 = (lane >> 4) * 4;
    #pragma unroll
    for (int mt = 0; mt < 4; ++mt)
        #pragma unroll
        for (int rg = 0; rg < 4; ++rg) {
            const int co = co0 + wv*64 + mt*16 + row4 + rg;
            const float bi = bias[co];
            #pragma unroll
            for (int jt = 0; jt < 4; ++jt)
                out[((size_t)b * CH + co) * NTOK + nn0 + jt*16 + col] =
                    acc[mt][jt][rg] + bi;
        }
}

// ---------------------------------------------------------------------------
extern "C" void kernel_launch(void* const* d_in, const int* in_sizes, int n_in,
                              void* d_out, int out_size, void* d_ws, size_t ws_size,
                              hipStream_t stream)
{
    (void)in_sizes; (void)n_in; (void)out_size; (void)ws_size;
    const float* x     = (const float*)d_in[0];
    const float* wqkv  = (const float*)d_in[1];
    const float* wproj = (const float*)d_in[2];
    const float* bproj = (const float*)d_in[3];
    float* out = (float*)d_out;

    float* qbuf = (float*)d_ws;
    float* kbuf = qbuf + NELEM;
    float* vbuf = kbuf + NELEM;
    unsigned long long* qmask = (unsigned long long*)(vbuf + NELEM);
    unsigned long long* kmask = qmask + (B_ * NH * NTOK);
    float* cs     = (float*)(kmask + (B_ * NH * NTOK));      // 192
    int*   csum_p = (int*)(cs + B_ * NH);                    // 192*4*64
    float* scale  = (float*)(csum_p + B_ * NH * 4 * HD);     // 192*64
    float* svs_g  = scale + B_ * NH * HD;                    // 192*64
    float* sumq_p = svs_g + B_ * NH * HD;                    // 768
    float* sumk_p = sumq_p + B_ * NH * 4;                    // 768
    float* vmax_p = sumk_p + B_ * NH * 4;                    // 192*4*64
    int*   fixq_g = (int*)(vmax_p + B_ * NH * 4 * HD);       // 16384
    int*   fixn_g = fixq_g + FIXCAP;                         // 1
    unsigned char* vt8 = (unsigned char*)kbuf;               // aliases dead k

    qkv_mfma<<<dim3(1296), 256, 0, stream>>>(x, wqkv, qbuf, kbuf, vbuf, fixn_g);
    reduce_pass<<<dim3(B_*NH, 4), 256, 0, stream>>>(qbuf, kbuf, vbuf,
        qmask, kmask, sumq_p, sumk_p, vmax_p, fixq_g, fixn_g);
    finalize<<<dim3(B_*NH), 64, 0, stream>>>(sumq_p, sumk_p, vmax_p,
        cs, svs_g, scale);
    vquant<<<dim3(B_*NH, 4), 256, 0, stream>>>(vbuf, svs_g, vt8, csum_p);
    fixup<<<dim3(32), 256, 0, stream>>>(x, wqkv, qmask, kmask, fixq_g, fixn_g);
    attn_i8<<<dim3(9, NH, B_), 256, 0, stream>>>(qmask, kmask, vt8, cs,
                                                 csum_p, scale, qbuf);
    proj_mfma<<<dim3(432), 256, 0, stream>>>(qbuf, wproj, bproj, out);
}

// Round 8
// 454.879 us; speedup vs baseline: 1.2625x; 1.2625x over previous
//
#include <hip/hip_runtime.h>
#include <hip/hip_bf16.h>

#define B_   16
#define NH   12
#define NTOK 576
#define HD   64
#define CH   768
#define NELEM (B_*NH*NTOK*HD)   // 7,077,888 floats per q/k/v buffer
#define VT8SZ (NTOK*HD)         // 36864 B per bh (int8 transposed V)
#define FIXCAP 16384
#define VPAD 176

typedef short v8s __attribute__((ext_vector_type(8)));
typedef short v4s __attribute__((ext_vector_type(4)));
typedef float v4f __attribute__((ext_vector_type(4)));
typedef int   v4i __attribute__((ext_vector_type(4)));

// split 4 fp32 into hi/lo bf16 (RN): f = hi + lo + O(2^-18 |f|)
static __device__ __forceinline__ void split4(const float* f, v4s& hi, v4s& lo)
{
    #pragma unroll
    for (int i = 0; i < 4; ++i) {
        __hip_bfloat16 h = __float2bfloat16(f[i]);
        float hf = __bfloat162float(h);
        __hip_bfloat16 l = __float2bfloat16(f[i] - hf);
        hi[i] = __builtin_bit_cast(short, h);
        lo[i] = __builtin_bit_cast(short, l);
    }
}

// ---------------------------------------------------------------------------
// K1: qkv[b,n,j] = sum_c x[b,c,n] * w_qkv[j,c]  via 3-term split-bf16 MFMA.
// (unchanged from round-7 passing version)
// ---------------------------------------------------------------------------
__global__ __launch_bounds__(256) void qkv_mfma(const float* __restrict__ x,
    const float* __restrict__ w, float* __restrict__ q, float* __restrict__ k,
    float* __restrict__ v, int* __restrict__ fixn_g)
{
    if (blockIdx.x == 0 && threadIdx.x == 0) *fixn_g = 0;

    __shared__ short Ah[64*40], Al[64*40];
    __shared__ short Bh[256*40], Bl[256*40];
    const int tid = threadIdx.x;
    int g = blockIdx.x;
    g = (g & 7) * 162 + (g >> 3);        // bijective: 1296 = 8*162
    const int b  = g / 81;
    const int rr = g % 81;
    const int jb = rr / 9;
    const int mb = rr % 9;
    const int n0 = mb * 64;
    const int j0 = jb * 256;
    const int lane = tid & 63, wv = tid >> 6;

    const int cq  = tid & 7;
    const int rw0 = tid >> 3;

    const float* xb  = x + (size_t)b * CH * NTOK + n0;
    const float* wbp = w + (size_t)j0 * CH;

    float areg[2][4];
    float breg[8][4];

    #pragma unroll
    for (int s = 0; s < 2; ++s) {
        const int nl = rw0 + 32*s;
        #pragma unroll
        for (int i = 0; i < 4; ++i)
            areg[s][i] = xb[(size_t)(cq*4 + i) * NTOK + nl];
    }
    #pragma unroll
    for (int s = 0; s < 8; ++s) {
        const int jl = rw0 + 32*s;
        const float4 t = *(const float4*)(wbp + (size_t)jl * CH + cq*4);
        breg[s][0]=t.x; breg[s][1]=t.y; breg[s][2]=t.z; breg[s][3]=t.w;
    }

    v4f acc[4][4];
    #pragma unroll
    for (int a = 0; a < 4; ++a)
        #pragma unroll
        for (int c = 0; c < 4; ++c) acc[a][c] = (v4f){0.f,0.f,0.f,0.f};

    for (int it = 0; it < 24; ++it) {
        __syncthreads();
        #pragma unroll
        for (int s = 0; s < 2; ++s) {
            v4s hi, lo; split4(areg[s], hi, lo);
            const int nl = rw0 + 32*s;
            *(v4s*)&Ah[nl*40 + cq*4] = hi;
            *(v4s*)&Al[nl*40 + cq*4] = lo;
        }
        #pragma unroll
        for (int s = 0; s < 8; ++s) {
            v4s hi, lo; split4(breg[s], hi, lo);
            const int jl = rw0 + 32*s;
            *(v4s*)&Bh[jl*40 + cq*4] = hi;
            *(v4s*)&Bl[jl*40 + cq*4] = lo;
        }
        __syncthreads();
        if (it < 23) {
            const int c0 = (it + 1) * 32;
            #pragma unroll
            for (int s = 0; s < 2; ++s) {
                const int nl = rw0 + 32*s;
                #pragma unroll
                for (int i = 0; i < 4; ++i)
                    areg[s][i] = xb[(size_t)(c0 + cq*4 + i) * NTOK + nl];
            }
            #pragma unroll
            for (int s = 0; s < 8; ++s) {
                const int jl = rw0 + 32*s;
                const float4 t = *(const float4*)(wbp + (size_t)jl * CH + c0 + cq*4);
                breg[s][0]=t.x; breg[s][1]=t.y; breg[s][2]=t.z; breg[s][3]=t.w;
            }
        }
        const int krow = lane & 15;
        const int k0   = (lane >> 4) * 8;
        v8s ah[4], al2[4], bh[4], bl[4];
        #pragma unroll
        for (int mt = 0; mt < 4; ++mt) {
            ah[mt]  = *(v8s*)&Ah[(mt*16 + krow)*40 + k0];
            al2[mt] = *(v8s*)&Al[(mt*16 + krow)*40 + k0];
        }
        #pragma unroll
        for (int jt = 0; jt < 4; ++jt) {
            bh[jt] = *(v8s*)&Bh[(wv*64 + jt*16 + krow)*40 + k0];
            bl[jt] = *(v8s*)&Bl[(wv*64 + jt*16 + krow)*40 + k0];
        }
        #pragma unroll
        for (int mt = 0; mt < 4; ++mt)
            #pragma unroll
            for (int jt = 0; jt < 4; ++jt) {
                acc[mt][jt] = __builtin_amdgcn_mfma_f32_16x16x32_bf16(ah[mt],  bh[jt], acc[mt][jt], 0, 0, 0);
                acc[mt][jt] = __builtin_amdgcn_mfma_f32_16x16x32_bf16(ah[mt],  bl[jt], acc[mt][jt], 0, 0, 0);
                acc[mt][jt] = __builtin_amdgcn_mfma_f32_16x16x32_bf16(al2[mt], bh[jt], acc[mt][jt], 0, 0, 0);
            }
    }

    const int sec = jb / 3;
    float* dst = (sec == 0) ? q : (sec == 1) ? k : v;
    const int h    = (jb % 3) * 4 + wv;
    const int col  = lane & 15;
    const int row4 = (lane >> 4) * 4;
    #pragma unroll
    for (int mt = 0; mt < 4; ++mt)
        #pragma unroll
        for (int jt = 0; jt < 4; ++jt) {
            const int dd = jt*16 + col;
            float* o = dst + (((size_t)b*NH + h)*NTOK + n0 + mt*16 + row4) * HD + dd;
            #pragma unroll
            for (int rg = 0; rg < 4; ++rg)
                o[(size_t)rg * HD] = acc[mt][jt][rg];
        }
}

// ---------------------------------------------------------------------------
// K2a: one pass over q,k,v per (bh, 144-row chunk): ballot sign masks,
// |q|/|k| partial sums, per-column |v| max partials, borderline queue.
// (unchanged from round-7)
// ---------------------------------------------------------------------------
__global__ __launch_bounds__(256) void reduce_pass(
    const float* __restrict__ q, const float* __restrict__ k,
    const float* __restrict__ v,
    unsigned long long* __restrict__ qm, unsigned long long* __restrict__ km,
    float* __restrict__ sumq_p, float* __restrict__ sumk_p,
    float* __restrict__ vmax_p, int* __restrict__ fixq_g,
    int* __restrict__ fixn_g)
{
    const int bh = blockIdx.x, ch = blockIdx.y;
    const int tid = threadIdx.x, lane = tid & 63, wv = tid >> 6;
    const size_t base = (size_t)bh * (NTOK * HD);
    const float* qb = q + base;
    const float* kb = k + base;
    const float* vb = v + base;
    const int n0 = ch * 144;

    float sq = 0.f, sk = 0.f, vmx = 0.f;
    for (int n = n0 + wv; n < n0 + 144; n += 4) {
        const float qv = qb[n*HD + lane];
        const float kv = kb[n*HD + lane];
        const float vv = vb[n*HD + lane];
        sq += fabsf(qv); sk += fabsf(kv); vmx = fmaxf(vmx, fabsf(vv));
        const unsigned long long mq = __ballot(qv >= 0.f);
        const unsigned long long mk = __ballot(kv >= 0.f);
        if (lane == 0) {
            qm[(size_t)bh*NTOK + n] = mq;
            km[(size_t)bh*NTOK + n] = mk;
        }
        if (fabsf(qv) < 1e-4f) {
            int s_ = atomicAdd(fixn_g, 1);
            if (s_ < FIXCAP) fixq_g[s_] = bh | (n << 8) | (lane << 18);
        }
        if (fabsf(kv) < 1e-4f) {
            int s_ = atomicAdd(fixn_g, 1);
            if (s_ < FIXCAP) fixq_g[s_] = bh | (n << 8) | (lane << 18) | (1 << 24);
        }
    }

    __shared__ float r1[256], r2[256], vm[256];
    r1[tid] = sq; r2[tid] = sk; vm[tid] = vmx;
    __syncthreads();
    for (int s = 128; s > 0; s >>= 1) {
        if (tid < s) { r1[tid] += r1[tid + s]; r2[tid] += r2[tid + s]; }
        __syncthreads();
    }
    if (tid == 0) { sumq_p[bh*4 + ch] = r1[0]; sumk_p[bh*4 + ch] = r2[0]; }
    if (tid < 64)
        vmax_p[((size_t)bh*4 + ch)*64 + tid] =
            fmaxf(fmaxf(vm[tid], vm[tid+64]), fmaxf(vm[tid+128], vm[tid+192]));
}

// ---------------------------------------------------------------------------
// K2b: finalize cs, svs, scale from partials. (unchanged)
// ---------------------------------------------------------------------------
__global__ __launch_bounds__(64) void finalize(
    const float* __restrict__ sumq_p, const float* __restrict__ sumk_p,
    const float* __restrict__ vmax_p, float* __restrict__ cs,
    float* __restrict__ svs_g, float* __restrict__ scale_g)
{
    const int bh = blockIdx.x, d = threadIdx.x;
    if (d == 0) {
        const float msq = (sumq_p[bh*4] + sumq_p[bh*4+1] + sumq_p[bh*4+2] +
                           sumq_p[bh*4+3]) * (1.f / (NTOK * HD));
        const float msk = (sumk_p[bh*4] + sumk_p[bh*4+1] + sumk_p[bh*4+2] +
                           sumk_p[bh*4+3]) * (1.f / (NTOK * HD));
        cs[bh] = msq * msk * 0.125f;
    }
    const float mm = fmaxf(
        fmaxf(vmax_p[((size_t)bh*4+0)*64 + d], vmax_p[((size_t)bh*4+1)*64 + d]),
        fmaxf(vmax_p[((size_t)bh*4+2)*64 + d], vmax_p[((size_t)bh*4+3)*64 + d]));
    const float svs = 127.f / (mm + 1e-6f);
    svs_g[bh*64 + d] = svs;
    scale_g[bh*64 + d] = (1.f/255.f) / (svs + 1e-6f);
}

// ---------------------------------------------------------------------------
// K2c: v -> int8 transposed [d][576] (via LDS), colsum partials. (unchanged)
// ---------------------------------------------------------------------------
__global__ __launch_bounds__(256) void vquant(const float* __restrict__ v,
    const float* __restrict__ svs_g, unsigned char* __restrict__ vt8,
    int* __restrict__ csum_p)
{
    const int bh = blockIdx.x, ch = blockIdx.y;
    const int tid = threadIdx.x, d = tid & 63;
    const float* vb = v + (size_t)bh * NTOK * HD + ch * 144 * HD;
    __shared__ unsigned char vt[64 * VPAD];
    __shared__ int cs_l[256];
    const float s = svs_g[bh*64 + d];
    int part = 0;
    for (int i = tid; i < 144 * 64; i += 256) {
        const int nl = i >> 6;
        const int iq = (int)rintf(vb[i] * s);       // in [-127,127]
        part += iq;
        vt[d*VPAD + nl] = (unsigned char)(iq & 255);
    }
    cs_l[tid] = part;
    __syncthreads();
    if (tid < 64)
        csum_p[((size_t)bh*4 + ch)*64 + tid] =
            cs_l[tid] + cs_l[tid+64] + cs_l[tid+128] + cs_l[tid+192];
    unsigned char* dst = vt8 + (size_t)bh * VT8SZ + ch * 144;
    for (int idx = tid; idx < 576; idx += 256) {
        const int row = idx / 9, seg = idx % 9;
        *(int4*)(dst + row*576 + seg*16) = *(const int4*)&vt[row*VPAD + seg*16];
    }
}

// ---------------------------------------------------------------------------
// K2d: borderline sign fixup — ONE WAVE PER ENTRY. Lanes cooperatively stage
// the x column (strided) and w row into per-wave LDS (parallel loads), then
// every lane runs the IDENTICAL strict-sequential fmaf chain over c=0..767
// (bit-identical to rounds 3/5/6/7); lane 0 applies the mask bit.
// Grid 64 x 256 (256 waves).
// ---------------------------------------------------------------------------
__global__ __launch_bounds__(256) void fixup(const float* __restrict__ x,
    const float* __restrict__ wqkv, unsigned long long* __restrict__ qm,
    unsigned long long* __restrict__ km, const int* __restrict__ fixq_g,
    const int* __restrict__ fixn_g)
{
    __shared__ float xls[4][CH];
    __shared__ float wls[4][CH];
    const int tid = threadIdx.x, lane = tid & 63, wv = tid >> 6;
    const int gw = blockIdx.x * 4 + wv;         // global wave id (0..255)
    const int total = min(*fixn_g, FIXCAP);

    for (int e = gw; e < total; e += 256) {
        const int rec = fixq_g[e];
        const int bh  = rec & 255;
        const int n   = (rec >> 8) & 1023;
        const int dd  = (rec >> 18) & 63;
        const int isk = (rec >> 24) & 1;
        const int b = bh / NH, h = bh % NH;
        const float* wr = wqkv + (size_t)(isk*CH + h*HD + dd) * CH;
        const float* xr = x + (size_t)b * CH * NTOK + n;
        // parallel staging: 12 strided x loads + 12 w loads per lane
        #pragma unroll
        for (int i = 0; i < 12; ++i) {
            const int c = i*64 + lane;
            xls[wv][c] = xr[(size_t)c * NTOK];
            wls[wv][c] = wr[c];
        }
        asm volatile("s_waitcnt vmcnt(0) lgkmcnt(0)" ::: "memory");
        // bit-exact sequential chain (same values, same order as before)
        float s = 0.f;
        #pragma unroll 8
        for (int c = 0; c < CH; ++c)
            s = fmaf(xls[wv][c], wls[wv][c], s);
        if (lane == 0) {
            unsigned* a32 = (unsigned*)((isk ? km : qm) + (size_t)bh*NTOK + n);
            const unsigned bit = 1u << (dd & 31);
            if (s >= 0.f) atomicOr(&a32[dd >> 5], bit);
            else          atomicAnd(&a32[dd >> 5], ~bit);
        }
        asm volatile("" ::: "memory");   // keep LDS reuse ordered across iters
    }
}

// ---------------------------------------------------------------------------
// K3: fused binary attention via exact int8 MFMA PV + 65-entry exp table.
// (unchanged from round-7 passing version)
// ---------------------------------------------------------------------------
__global__ __launch_bounds__(256) void attn_i8(
    const unsigned long long* __restrict__ qm,
    const unsigned long long* __restrict__ km,
    const unsigned char* __restrict__ vt8, const float* __restrict__ cs,
    const int* __restrict__ csum_p, const float* __restrict__ scale_g,
    float* __restrict__ pre)
{
    const int tid = threadIdx.x;
    const int t0 = blockIdx.x << 6;
    const int h  = blockIdx.y;
    const int b  = blockIdx.z;
    const int bh = b * NH + h;

    __shared__ unsigned long long kml[NTOK];
    __shared__ unsigned long long qml[64];
    __shared__ float rs[64];
    __shared__ float table[65];
    __shared__ unsigned char vt[64*592];

    for (int i = tid; i < NTOK; i += 256) kml[i] = km[(size_t)bh * NTOK + i];
    if (tid < 64) qml[tid] = qm[(size_t)bh * NTOK + t0 + tid];
    const float c = cs[bh];
    if (tid < 65) table[tid] = __expf(c * (float)(64 - 2 * tid));
    {
        const unsigned char* src = vt8 + (size_t)bh * VT8SZ;
        #pragma unroll
        for (int t = 0; t < 9; ++t) {
            const int idx = tid + t*256;
            const int row = idx / 36, seg = idx % 36;
            *(int4*)&vt[row*592 + seg*16] = *(const int4*)(src + row*576 + seg*16);
        }
    }
    __syncthreads();

    const int wv = tid >> 6, lane = tid & 63;
    for (int r = wv; r < 64; r += 4) {
        const unsigned long long qq = qml[r];
        float s = 0.f;
        for (int m = lane; m < NTOK; m += 64) {
            const int pc = __popcll(qq ^ kml[m]);
            s += table[pc];
        }
        #pragma unroll
        for (int off = 32; off; off >>= 1) s += __shfl_xor(s, off, 64);
        if (lane == 0) rs[r] = 1.f / s;
    }
    __syncthreads();

    const int row_l = lane & 15;
    const int kgrp  = lane >> 4;
    const unsigned long long uq = qml[wv*16 + row_l];
    const float rsr = rs[wv*16 + row_l];
    v4i acc[4];
    #pragma unroll
    for (int jt = 0; jt < 4; ++jt) acc[jt] = (v4i){0,0,0,0};

    for (int ch = 0; ch < 9; ++ch) {
        const int mb = ch*64 + kgrp*16;
        int wds[4];
        #pragma unroll
        for (int wq = 0; wq < 4; ++wq) {
            int pk = 0;
            #pragma unroll
            for (int j = 0; j < 4; ++j) {
                const int pc = __popcll(uq ^ kml[mb + wq*4 + j]);
                const float p = table[pc] * rsr;
                const int iq = (int)rintf(p * 255.f) - 128;
                pk |= (iq & 255) << (8*j);
            }
            wds[wq] = pk;
        }
        v4i a; a[0]=wds[0]; a[1]=wds[1]; a[2]=wds[2]; a[3]=wds[3];
        #pragma unroll
        for (int jt = 0; jt < 4; ++jt) {
            const v4i bfr = *(const v4i*)&vt[(jt*16 + row_l)*592 + mb];
            acc[jt] = __builtin_amdgcn_mfma_i32_16x16x64_i8(a, bfr, acc[jt], 0, 0, 0);
        }
    }

    const int rb = kgrp * 4;
    #pragma unroll
    for (int jt = 0; jt < 4; ++jt) {
        const int dd = jt*16 + row_l;
        const int csd = csum_p[((size_t)bh*4+0)*64 + dd] +
                        csum_p[((size_t)bh*4+1)*64 + dd] +
                        csum_p[((size_t)bh*4+2)*64 + dd] +
                        csum_p[((size_t)bh*4+3)*64 + dd];
        const float scd = scale_g[bh*64 + dd];
        #pragma unroll
        for (int rg = 0; rg < 4; ++rg) {
            const int n = t0 + wv*16 + rb + rg;
            pre[((size_t)b * NTOK + n) * CH + h * HD + dd] =
                (float)(acc[jt][rg] + 128 * csd) * scd;
        }
    }
}

// ---------------------------------------------------------------------------
// K4: out[b,co,n] = sum_j pre[b,n,j]*w_proj[co,j] + bias[co], split-bf16 MFMA.
// (unchanged from round-7 passing version)
// ---------------------------------------------------------------------------
__global__ __launch_bounds__(256) void proj_mfma(const float* __restrict__ pre,
    const float* __restrict__ w, const float* __restrict__ bias,
    float* __restrict__ out)
{
    __shared__ short Awh[256*40], Awl[256*40];
    __shared__ short Bph[64*40],  Bpl[64*40];
    const int tid = threadIdx.x;
    int g = blockIdx.x;
    g = (g & 7) * 54 + (g >> 3);         // bijective: 432 = 8*54
    const int b  = g / 27;
    const int rr = g % 27;
    const int cb = rr / 9;
    const int nb = rr % 9;
    const int co0 = cb * 256;
    const int nn0 = nb * 64;
    const int lane = tid & 63, wv = tid >> 6;
    const int cq  = tid & 7;
    const int rw0 = tid >> 3;

    const float* wp = w + (size_t)co0 * CH;
    const float* pb = pre + ((size_t)b * NTOK + nn0) * CH;

    float areg[8][4];
    float breg[2][4];

    #pragma unroll
    for (int s = 0; s < 8; ++s) {
        const int cl = rw0 + 32*s;
        const float4 t = *(const float4*)(wp + (size_t)cl * CH + cq*4);
        areg[s][0]=t.x; areg[s][1]=t.y; areg[s][2]=t.z; areg[s][3]=t.w;
    }
    #pragma unroll
    for (int s = 0; s < 2; ++s) {
        const int nl = rw0 + 32*s;
        const float4 t = *(const float4*)(pb + (size_t)nl * CH + cq*4);
        breg[s][0]=t.x; breg[s][1]=t.y; breg[s][2]=t.z; breg[s][3]=t.w;
    }

    v4f acc[4][4];
    #pragma unroll
    for (int a = 0; a < 4; ++a)
        #pragma unroll
        for (int c = 0; c < 4; ++c) acc[a][c] = (v4f){0.f,0.f,0.f,0.f};

    for (int it = 0; it < 24; ++it) {
        __syncthreads();
        #pragma unroll
        for (int s = 0; s < 8; ++s) {
            v4s hi, lo; split4(areg[s], hi, lo);
            const int cl = rw0 + 32*s;
            *(v4s*)&Awh[cl*40 + cq*4] = hi;
            *(v4s*)&Awl[cl*40 + cq*4] = lo;
        }
        #pragma unroll
        for (int s = 0; s < 2; ++s) {
            v4s hi, lo; split4(breg[s], hi, lo);
            const int nl = rw0 + 32*s;
            *(v4s*)&Bph[nl*40 + cq*4] = hi;
            *(v4s*)&Bpl[nl*40 + cq*4] = lo;
        }
        __syncthreads();
        if (it < 23) {
            const int k0g = (it + 1) * 32;
            #pragma unroll
            for (int s = 0; s < 8; ++s) {
                const int cl = rw0 + 32*s;
                const float4 t = *(const float4*)(wp + (size_t)cl * CH + k0g + cq*4);
                areg[s][0]=t.x; areg[s][1]=t.y; areg[s][2]=t.z; areg[s][3]=t.w;
            }
            #pragma unroll
            for (int s = 0; s < 2; ++s) {
                const int nl = rw0 + 32*s;
                const float4 t = *(const float4*)(pb + (size_t)nl * CH + k0g + cq*4);
                breg[s][0]=t.x; breg[s][1]=t.y; breg[s][2]=t.z; breg[s][3]=t.w;
            }
        }
        const int krow = lane & 15;
        const int k0   = (lane >> 4) * 8;
        v8s ah[4], al2[4], bh[4], bl[4];
        #pragma unroll
        for (int mt = 0; mt < 4; ++mt) {
            ah[mt]  = *(v8s*)&Awh[(wv*64 + mt*16 + krow)*40 + k0];
            al2[mt] = *(v8s*)&Awl[(wv*64 + mt*16 + krow)*40 + k0];
        }
        #pragma unroll
        for (int jt = 0; jt < 4; ++jt) {
            bh[jt] = *(v8s*)&Bph[(jt*16 + krow)*40 + k0];
            bl[jt] = *(v8s*)&Bpl[(jt*16 + krow)*40 + k0];
        }
        #pragma unroll
        for (int mt = 0; mt < 4; ++mt)
            #pragma unroll
            for (int jt = 0; jt < 4; ++jt) {
                acc[mt][jt] = __builtin_amdgcn_mfma_f32_16x16x32_bf16(ah[mt],  bh[jt], acc[mt][jt], 0, 0, 0);
                acc[mt][jt] = __builtin_amdgcn_mfma_f32_16x16x32_bf16(ah[mt],  bl[jt], acc[mt][jt], 0, 0, 0);
                acc[mt][jt] = __builtin_amdgcn_mfma_f32_16x16x32_bf16(al2[mt], bh[jt], acc[mt][jt], 0, 0, 0);
            }
    }

    const int col  = lane & 15;
    const int row4 = (lane >> 4) * 4;
    #pragma unroll
    for (int mt = 0; mt < 4; ++mt)
        #pragma unroll
        for (int rg = 0; rg < 4; ++rg) {
            const int co = co0 + wv*64 + mt*16 + row4 + rg;
            const float bi = bias[co];
            #pragma unroll
            for (int jt = 0; jt < 4; ++jt)
                out[((size_t)b * CH + co) * NTOK + nn0 + jt*16 + col] =
                    acc[mt][jt][rg] + bi;
        }
}

// ---------------------------------------------------------------------------
extern "C" void kernel_launch(void* const* d_in, const int* in_sizes, int n_in,
                              void* d_out, int out_size, void* d_ws, size_t ws_size,
                              hipStream_t stream)
{
    (void)in_sizes; (void)n_in; (void)out_size; (void)ws_size;
    const float* x     = (const float*)d_in[0];
    const float* wqkv  = (const float*)d_in[1];
    const float* wproj = (const float*)d_in[2];
    const float* bproj = (const float*)d_in[3];
    float* out = (float*)d_out;

    float* qbuf = (float*)d_ws;
    float* kbuf = qbuf + NELEM;
    float* vbuf = kbuf + NELEM;
    unsigned long long* qmask = (unsigned long long*)(vbuf + NELEM);
    unsigned long long* kmask = qmask + (B_ * NH * NTOK);
    float* cs     = (float*)(kmask + (B_ * NH * NTOK));      // 192
    int*   csum_p = (int*)(cs + B_ * NH);                    // 192*4*64
    float* scale  = (float*)(csum_p + B_ * NH * 4 * HD);     // 192*64
    float* svs_g  = scale + B_ * NH * HD;                    // 192*64
    float* sumq_p = svs_g + B_ * NH * HD;                    // 768
    float* sumk_p = sumq_p + B_ * NH * 4;                    // 768
    float* vmax_p = sumk_p + B_ * NH * 4;                    // 192*4*64
    int*   fixq_g = (int*)(vmax_p + B_ * NH * 4 * HD);       // 16384
    int*   fixn_g = fixq_g + FIXCAP;                         // 1
    unsigned char* vt8 = (unsigned char*)kbuf;               // aliases dead k

    qkv_mfma<<<dim3(1296), 256, 0, stream>>>(x, wqkv, qbuf, kbuf, vbuf, fixn_g);
    reduce_pass<<<dim3(B_*NH, 4), 256, 0, stream>>>(qbuf, kbuf, vbuf,
        qmask, kmask, sumq_p, sumk_p, vmax_p, fixq_g, fixn_g);
    finalize<<<dim3(B_*NH), 64, 0, stream>>>(sumq_p, sumk_p, vmax_p,
        cs, svs_g, scale);
    vquant<<<dim3(B_*NH, 4), 256, 0, stream>>>(vbuf, svs_g, vt8, csum_p);
    fixup<<<dim3(64), 256, 0, stream>>>(x, wqkv, qmask, kmask, fixq_g, fixn_g);
    attn_i8<<<dim3(9, NH, B_), 256, 0, stream>>>(qmask, kmask, vt8, cs,
                                                 csum_p, scale, qbuf);
    proj_mfma<<<dim3(432), 256, 0, stream>>>(qbuf, wproj, bproj, out);
}

// Round 11
// 442.796 us; speedup vs baseline: 1.2970x; 1.0273x over previous
//
#include <hip/hip_runtime.h>
#include <hip/hip_bf16.h>

#define B_   16
#define NH   12
#define NTOK 576
#define HD   64
#define CH   768
#define NELEM (B_*NH*NTOK*HD)   // 7,077,888
#define VT8SZ (NTOK*HD)         // 36864 B per bh
#define FIXCAP 16384
#define VPAD 176

typedef short v8s __attribute__((ext_vector_type(8)));
typedef short v4s __attribute__((ext_vector_type(4)));
typedef float v4f __attribute__((ext_vector_type(4)));
typedef int   v4i __attribute__((ext_vector_type(4)));

static __device__ __forceinline__ void split1(float f, short& h, short& l)
{
    __hip_bfloat16 bh = __float2bfloat16(f);
    float hf = __bfloat162float(bh);
    __hip_bfloat16 bl = __float2bfloat16(f - hf);
    h = __builtin_bit_cast(short, bh);
    l = __builtin_bit_cast(short, bl);
}

// ---------------------------------------------------------------------------
// K0a: x [b][c][n] fp32 -> xT hi/lo bf16 [b][n][c] (transpose via LDS).
// Grid (9 n-tiles, 12 c-tiles, 16 b) x 256.
// ---------------------------------------------------------------------------
__global__ __launch_bounds__(256) void splitx(const float* __restrict__ x,
    short* __restrict__ xh, short* __restrict__ xl, int* __restrict__ fixn_g)
{
    if (blockIdx.x == 0 && blockIdx.y == 0 && blockIdx.z == 0 &&
        threadIdx.x == 0) *fixn_g = 0;
    __shared__ float t[64][65];
    const int n0 = blockIdx.x * 64, c0 = blockIdx.y * 64, b = blockIdx.z;
    const int tid = threadIdx.x;
    const int r4 = tid >> 6, cc = tid & 63;
    #pragma unroll
    for (int i = 0; i < 16; ++i) {
        const int cl = r4 + i*4;
        t[cl][cc] = x[((size_t)b*CH + c0 + cl)*NTOK + n0 + cc];
    }
    __syncthreads();
    #pragma unroll
    for (int i = 0; i < 16; ++i) {
        const int nl = r4 + i*4;
        short h, l; split1(t[cc][nl], h, l);
        const size_t o = ((size_t)b*NTOK + n0 + nl)*CH + c0 + cc;
        xh[o] = h; xl[o] = l;
    }
}

// ---------------------------------------------------------------------------
// K0b: w_qkv (2304x768) + w_proj (768x768) -> hi/lo bf16, same layout.
// 576 blocks x 256 x 16 elems.
// ---------------------------------------------------------------------------
__global__ __launch_bounds__(256) void splitw(const float* __restrict__ wq,
    const float* __restrict__ wp, short* __restrict__ wqh,
    short* __restrict__ wql, short* __restrict__ wph, short* __restrict__ wpl)
{
    const size_t e0 = (size_t)blockIdx.x * 4096 + threadIdx.x;
    #pragma unroll
    for (int i = 0; i < 16; ++i) {
        const size_t e = e0 + (size_t)i * 256;
        short h, l;
        if (e < (size_t)2304*768) {
            split1(wq[e], h, l);
            wqh[e] = h; wql[e] = l;
        } else {
            const size_t o = e - (size_t)2304*768;
            split1(wp[o], h, l);
            wph[o] = h; wpl[o] = l;
        }
    }
}

// ---------------------------------------------------------------------------
// K1: qkv GEMM via 3-term split-bf16 MFMA from pre-split operands.
// Epilogue fusion: q/k are NEVER written — masks (ballot), |sum| partials
// (9 deterministic slots/bh), borderline queue from registers; v written
// fp32 + per-column |v| max partials. GEMM bits identical to round 8.
// ---------------------------------------------------------------------------
__global__ __launch_bounds__(256) void qkv_mfma(const short* __restrict__ xh,
    const short* __restrict__ xl, const short* __restrict__ wh,
    const short* __restrict__ wl, float* __restrict__ v,
    unsigned long long* __restrict__ qm, unsigned long long* __restrict__ km,
    float* __restrict__ sumq_p, float* __restrict__ sumk_p,
    float* __restrict__ vmax_p, int* __restrict__ fixq_g,
    int* __restrict__ fixn_g)
{
    __shared__ short Ah[64*40], Al[64*40];
    __shared__ short Bh[256*40], Bl[256*40];
    const int tid = threadIdx.x;
    int g = blockIdx.x;
    g = (g & 7) * 162 + (g >> 3);        // bijective: 1296 = 8*162
    const int b  = g / 81;
    const int rr = g % 81;
    const int jb = rr / 9;
    const int mb = rr % 9;
    const int n0 = mb * 64;
    const int j0 = jb * 256;
    const int lane = tid & 63, wv = tid >> 6;
    const int cq  = tid & 7;
    const int rw0 = tid >> 3;

    const short* xbh = xh + ((size_t)b*NTOK + n0)*CH;
    const short* xbl = xl + ((size_t)b*NTOK + n0)*CH;
    const short* wbh = wh + (size_t)j0*CH;
    const short* wbl = wl + (size_t)j0*CH;

    v4s Ahr[2], Alr[2], Bhr[8], Blr[8];
    #pragma unroll
    for (int s = 0; s < 2; ++s) {
        const size_t o = (size_t)(rw0 + 32*s)*CH + cq*4;
        Ahr[s] = *(const v4s*)&xbh[o];
        Alr[s] = *(const v4s*)&xbl[o];
    }
    #pragma unroll
    for (int s = 0; s < 8; ++s) {
        const size_t o = (size_t)(rw0 + 32*s)*CH + cq*4;
        Bhr[s] = *(const v4s*)&wbh[o];
        Blr[s] = *(const v4s*)&wbl[o];
    }

    v4f acc[4][4];
    #pragma unroll
    for (int a = 0; a < 4; ++a)
        #pragma unroll
        for (int c = 0; c < 4; ++c) acc[a][c] = (v4f){0.f,0.f,0.f,0.f};

    for (int it = 0; it < 24; ++it) {
        __syncthreads();
        #pragma unroll
        for (int s = 0; s < 2; ++s) {
            const int nl = rw0 + 32*s;
            *(v4s*)&Ah[nl*40 + cq*4] = Ahr[s];
            *(v4s*)&Al[nl*40 + cq*4] = Alr[s];
        }
        #pragma unroll
        for (int s = 0; s < 8; ++s) {
            const int jl = rw0 + 32*s;
            *(v4s*)&Bh[jl*40 + cq*4] = Bhr[s];
            *(v4s*)&Bl[jl*40 + cq*4] = Blr[s];
        }
        __syncthreads();
        if (it < 23) {
            const int c0 = (it + 1) * 32;
            #pragma unroll
            for (int s = 0; s < 2; ++s) {
                const size_t o = (size_t)(rw0 + 32*s)*CH + c0 + cq*4;
                Ahr[s] = *(const v4s*)&xbh[o];
                Alr[s] = *(const v4s*)&xbl[o];
            }
            #pragma unroll
            for (int s = 0; s < 8; ++s) {
                const size_t o = (size_t)(rw0 + 32*s)*CH + c0 + cq*4;
                Bhr[s] = *(const v4s*)&wbh[o];
                Blr[s] = *(const v4s*)&wbl[o];
            }
        }
        const int krow = lane & 15;
        const int k0   = (lane >> 4) * 8;
        v8s ah[4], al2[4], bh[4], bl[4];
        #pragma unroll
        for (int mt = 0; mt < 4; ++mt) {
            ah[mt]  = *(v8s*)&Ah[(mt*16 + krow)*40 + k0];
            al2[mt] = *(v8s*)&Al[(mt*16 + krow)*40 + k0];
        }
        #pragma unroll
        for (int jt = 0; jt < 4; ++jt) {
            bh[jt] = *(v8s*)&Bh[(wv*64 + jt*16 + krow)*40 + k0];
            bl[jt] = *(v8s*)&Bl[(wv*64 + jt*16 + krow)*40 + k0];
        }
        #pragma unroll
        for (int mt = 0; mt < 4; ++mt)
            #pragma unroll
            for (int jt = 0; jt < 4; ++jt) {
                acc[mt][jt] = __builtin_amdgcn_mfma_f32_16x16x32_bf16(ah[mt],  bh[jt], acc[mt][jt], 0, 0, 0);
                acc[mt][jt] = __builtin_amdgcn_mfma_f32_16x16x32_bf16(ah[mt],  bl[jt], acc[mt][jt], 0, 0, 0);
                acc[mt][jt] = __builtin_amdgcn_mfma_f32_16x16x32_bf16(al2[mt], bh[jt], acc[mt][jt], 0, 0, 0);
            }
    }

    const int sec = jb / 3;
    const int h   = (jb % 3) * 4 + wv;
    const int bh  = b * NH + h;
    const int col = lane & 15, g4 = lane >> 4;

    if (sec < 2) {
        unsigned long long* mask = sec ? km : qm;
        float* sump = sec ? sumk_p : sumq_p;
        float asum = 0.f;
        #pragma unroll
        for (int mt = 0; mt < 4; ++mt)
            #pragma unroll
            for (int jt = 0; jt < 4; ++jt)
                #pragma unroll
                for (int rg = 0; rg < 4; ++rg)
                    asum += fabsf(acc[mt][jt][rg]);
        #pragma unroll
        for (int off = 32; off; off >>= 1) asum += __shfl_xor(asum, off, 64);
        if (lane == 0) sump[bh*9 + mb] = asum;

        #pragma unroll
        for (int mt = 0; mt < 4; ++mt)
            #pragma unroll
            for (int rg = 0; rg < 4; ++rg) {
                const unsigned long long b0 = __ballot(acc[mt][0][rg] >= 0.f);
                const unsigned long long b1 = __ballot(acc[mt][1][rg] >= 0.f);
                const unsigned long long b2 = __ballot(acc[mt][2][rg] >= 0.f);
                const unsigned long long b3 = __ballot(acc[mt][3][rg] >= 0.f);
                if (col == 0) {
                    const int sh = g4 * 16;
                    const unsigned long long m =
                          ((b0 >> sh) & 0xFFFFull)
                        | (((b1 >> sh) & 0xFFFFull) << 16)
                        | (((b2 >> sh) & 0xFFFFull) << 32)
                        | (((b3 >> sh) & 0xFFFFull) << 48);
                    const int n = n0 + mt*16 + g4*4 + rg;
                    mask[(size_t)bh*NTOK + n] = m;
                }
            }
        #pragma unroll
        for (int mt = 0; mt < 4; ++mt)
            #pragma unroll
            for (int jt = 0; jt < 4; ++jt)
                #pragma unroll
                for (int rg = 0; rg < 4; ++rg)
                    if (fabsf(acc[mt][jt][rg]) < 1e-4f) {
                        const int n  = n0 + mt*16 + g4*4 + rg;
                        const int dd = jt*16 + col;
                        int s_ = atomicAdd(fixn_g, 1);
                        if (s_ < FIXCAP)
                            fixq_g[s_] = bh | (n<<8) | (dd<<18) | (sec<<24);
                    }
    } else {
        const int row4 = g4 * 4;
        #pragma unroll
        for (int mt = 0; mt < 4; ++mt)
            #pragma unroll
            for (int jt = 0; jt < 4; ++jt) {
                const int dd = jt*16 + col;
                float* o = v + (((size_t)bh)*NTOK + n0 + mt*16 + row4)*HD + dd;
                #pragma unroll
                for (int rg = 0; rg < 4; ++rg)
                    o[(size_t)rg * HD] = acc[mt][jt][rg];
            }
        #pragma unroll
        for (int jt = 0; jt < 4; ++jt) {
            float m = 0.f;
            #pragma unroll
            for (int mt = 0; mt < 4; ++mt)
                #pragma unroll
                for (int rg = 0; rg < 4; ++rg)
                    m = fmaxf(m, fabsf(acc[mt][jt][rg]));
            m = fmaxf(m, __shfl_xor(m, 16, 64));
            m = fmaxf(m, __shfl_xor(m, 32, 64));
            if (g4 == 0)
                vmax_p[((size_t)bh*9 + mb)*64 + jt*16 + col] = m;
        }
    }
}

// ---------------------------------------------------------------------------
// K2b: finalize cs (9 ordered partials), svs/scale from vmax partials.
// ---------------------------------------------------------------------------
__global__ __launch_bounds__(64) void finalize(
    const float* __restrict__ sumq_p, const float* __restrict__ sumk_p,
    const float* __restrict__ vmax_p, float* __restrict__ cs,
    float* __restrict__ svs_g, float* __restrict__ scale_g)
{
    const int bh = blockIdx.x, d = threadIdx.x;
    if (d == 0) {
        float sq = 0.f, sk = 0.f;
        #pragma unroll
        for (int i = 0; i < 9; ++i) { sq += sumq_p[bh*9+i]; sk += sumk_p[bh*9+i]; }
        cs[bh] = (sq * (1.f/(NTOK*HD))) * (sk * (1.f/(NTOK*HD))) * 0.125f;
    }
    float mm = 0.f;
    #pragma unroll
    for (int i = 0; i < 9; ++i)
        mm = fmaxf(mm, vmax_p[((size_t)bh*9 + i)*64 + d]);
    const float svs = 127.f / (mm + 1e-6f);
    svs_g[bh*64 + d] = svs;
    scale_g[bh*64 + d] = (1.f/255.f) / (svs + 1e-6f);
}

// ---------------------------------------------------------------------------
// K2c: v -> int8 transposed [d][576] (via LDS), colsum partials.
// ---------------------------------------------------------------------------
__global__ __launch_bounds__(256) void vquant(const float* __restrict__ v,
    const float* __restrict__ svs_g, unsigned char* __restrict__ vt8,
    int* __restrict__ csum_p)
{
    const int bh = blockIdx.x, ch = blockIdx.y;
    const int tid = threadIdx.x, d = tid & 63;
    const float* vb = v + (size_t)bh * NTOK * HD + ch * 144 * HD;
    __shared__ unsigned char vt[64 * VPAD];
    __shared__ int cs_l[256];
    const float s = svs_g[bh*64 + d];
    int part = 0;
    for (int i = tid; i < 144 * 64; i += 256) {
        const int nl = i >> 6;
        const int iq = (int)rintf(vb[i] * s);
        part += iq;
        vt[d*VPAD + nl] = (unsigned char)(iq & 255);
    }
    cs_l[tid] = part;
    __syncthreads();
    if (tid < 64)
        csum_p[((size_t)bh*4 + ch)*64 + tid] =
            cs_l[tid] + cs_l[tid+64] + cs_l[tid+128] + cs_l[tid+192];
    unsigned char* dst = vt8 + (size_t)bh * VT8SZ + ch * 144;
    for (int idx = tid; idx < 576; idx += 256) {
        const int row = idx / 9, seg = idx % 9;
        *(int4*)(dst + row*576 + seg*16) = *(const int4*)&vt[row*VPAD + seg*16];
    }
}

// ---------------------------------------------------------------------------
// K2d: borderline sign fixup — one wave per entry, LDS-staged operands,
// bit-exact sequential fmaf chain over c. (unchanged from round 8)
// ---------------------------------------------------------------------------
__global__ __launch_bounds__(256) void fixup(const float* __restrict__ x,
    const float* __restrict__ wqkv, unsigned long long* __restrict__ qm,
    unsigned long long* __restrict__ km, const int* __restrict__ fixq_g,
    const int* __restrict__ fixn_g)
{
    __shared__ float xls[4][CH];
    __shared__ float wls[4][CH];
    const int tid = threadIdx.x, lane = tid & 63, wv = tid >> 6;
    const int gw = blockIdx.x * 4 + wv;
    const int total = min(*fixn_g, FIXCAP);

    for (int e = gw; e < total; e += 256) {
        const int rec = fixq_g[e];
        const int bh  = rec & 255;
        const int n   = (rec >> 8) & 1023;
        const int dd  = (rec >> 18) & 63;
        const int isk = (rec >> 24) & 1;
        const int b = bh / NH, h = bh % NH;
        const float* wr = wqkv + (size_t)(isk*CH + h*HD + dd) * CH;
        const float* xr = x + (size_t)b * CH * NTOK + n;
        #pragma unroll
        for (int i = 0; i < 12; ++i) {
            const int c = i*64 + lane;
            xls[wv][c] = xr[(size_t)c * NTOK];
            wls[wv][c] = wr[c];
        }
        asm volatile("s_waitcnt vmcnt(0) lgkmcnt(0)" ::: "memory");
        float s = 0.f;
        #pragma unroll 8
        for (int c = 0; c < CH; ++c)
            s = fmaf(xls[wv][c], wls[wv][c], s);
        if (lane == 0) {
            unsigned* a32 = (unsigned*)((isk ? km : qm) + (size_t)bh*NTOK + n);
            const unsigned bit = 1u << (dd & 31);
            if (s >= 0.f) atomicOr(&a32[dd >> 5], bit);
            else          atomicAnd(&a32[dd >> 5], ~bit);
        }
        asm volatile("" ::: "memory");
    }
}

// ---------------------------------------------------------------------------
// K3: binary attention via exact int8 MFMA PV + 65-entry exp table.
// Epilogue now writes preh/prel (bf16 hi/lo split of the fp32 value).
// ---------------------------------------------------------------------------
__global__ __launch_bounds__(256) void attn_i8(
    const unsigned long long* __restrict__ qm,
    const unsigned long long* __restrict__ km,
    const unsigned char* __restrict__ vt8, const float* __restrict__ cs,
    const int* __restrict__ csum_p, const float* __restrict__ scale_g,
    short* __restrict__ preh, short* __restrict__ prel)
{
    const int tid = threadIdx.x;
    const int t0 = blockIdx.x << 6;
    const int h  = blockIdx.y;
    const int b  = blockIdx.z;
    const int bh = b * NH + h;

    __shared__ unsigned long long kml[NTOK];
    __shared__ unsigned long long qml[64];
    __shared__ float rs[64];
    __shared__ float table[65];
    __shared__ unsigned char vt[64*592];

    for (int i = tid; i < NTOK; i += 256) kml[i] = km[(size_t)bh * NTOK + i];
    if (tid < 64) qml[tid] = qm[(size_t)bh * NTOK + t0 + tid];
    const float c = cs[bh];
    if (tid < 65) table[tid] = __expf(c * (float)(64 - 2 * tid));
    {
        const unsigned char* src = vt8 + (size_t)bh * VT8SZ;
        #pragma unroll
        for (int t = 0; t < 9; ++t) {
            const int idx = tid + t*256;
            const int row = idx / 36, seg = idx % 36;
            *(int4*)&vt[row*592 + seg*16] = *(const int4*)(src + row*576 + seg*16);
        }
    }
    __syncthreads();

    const int wv = tid >> 6, lane = tid & 63;
    for (int r = wv; r < 64; r += 4) {
        const unsigned long long qq = qml[r];
        float s = 0.f;
        for (int m = lane; m < NTOK; m += 64) {
            const int pc = __popcll(qq ^ kml[m]);
            s += table[pc];
        }
        #pragma unroll
        for (int off = 32; off; off >>= 1) s += __shfl_xor(s, off, 64);
        if (lane == 0) rs[r] = 1.f / s;
    }
    __syncthreads();

    const int row_l = lane & 15;
    const int kgrp  = lane >> 4;
    const unsigned long long uq = qml[wv*16 + row_l];
    const float rsr = rs[wv*16 + row_l];
    v4i acc[4];
    #pragma unroll
    for (int jt = 0; jt < 4; ++jt) acc[jt] = (v4i){0,0,0,0};

    for (int ch = 0; ch < 9; ++ch) {
        const int mb = ch*64 + kgrp*16;
        int wds[4];
        #pragma unroll
        for (int wq = 0; wq < 4; ++wq) {
            int pk = 0;
            #pragma unroll
            for (int j = 0; j < 4; ++j) {
                const int pc = __popcll(uq ^ kml[mb + wq*4 + j]);
                const float p = table[pc] * rsr;
                const int iq = (int)rintf(p * 255.f) - 128;
                pk |= (iq & 255) << (8*j);
            }
            wds[wq] = pk;
        }
        v4i a; a[0]=wds[0]; a[1]=wds[1]; a[2]=wds[2]; a[3]=wds[3];
        #pragma unroll
        for (int jt = 0; jt < 4; ++jt) {
            const v4i bfr = *(const v4i*)&vt[(jt*16 + row_l)*592 + mb];
            acc[jt] = __builtin_amdgcn_mfma_i32_16x16x64_i8(a, bfr, acc[jt], 0, 0, 0);
        }
    }

    const int rb = kgrp * 4;
    #pragma unroll
    for (int jt = 0; jt < 4; ++jt) {
        const int dd = jt*16 + row_l;
        const int csd = csum_p[((size_t)bh*4+0)*64 + dd] +
                        csum_p[((size_t)bh*4+1)*64 + dd] +
                        csum_p[((size_t)bh*4+2)*64 + dd] +
                        csum_p[((size_t)bh*4+3)*64 + dd];
        const float scd = scale_g[bh*64 + dd];
        #pragma unroll
        for (int rg = 0; rg < 4; ++rg) {
            const int n = t0 + wv*16 + rb + rg;
            const float f = (float)(acc[jt][rg] + 128 * csd) * scd;
            short hh, ll; split1(f, hh, ll);
            const size_t idx = ((size_t)b * NTOK + n) * CH + h * HD + dd;
            preh[idx] = hh; prel[idx] = ll;
        }
    }
}

// ---------------------------------------------------------------------------
// K4: proj GEMM, split-bf16 MFMA from pre-split operands.
// ---------------------------------------------------------------------------
__global__ __launch_bounds__(256) void proj_mfma(const short* __restrict__ ph,
    const short* __restrict__ pl, const short* __restrict__ wh,
    const short* __restrict__ wl, const float* __restrict__ bias,
    float* __restrict__ out)
{
    __shared__ short Awh[256*40], Awl[256*40];
    __shared__ short Bph[64*40],  Bpl[64*40];
    const int tid = threadIdx.x;
    int g = blockIdx.x;
    g = (g & 7) * 54 + (g >> 3);         // bijective: 432 = 8*54
    const int b  = g / 27;
    const int rr = g % 27;
    const int cb = rr / 9;
    const int nb = rr % 9;
    const int co0 = cb * 256;
    const int nn0 = nb * 64;
    const int lane = tid & 63, wv = tid >> 6;
    const int cq  = tid & 7;
    const int rw0 = tid >> 3;

    const short* wph2 = wh + (size_t)co0 * CH;
    const short* wpl2 = wl + (size_t)co0 * CH;
    const short* pbh  = ph + ((size_t)b * NTOK + nn0) * CH;
    const short* pbl  = pl + ((size_t)b * NTOK + nn0) * CH;

    v4s Ahr[8], Alr[8], Bhr[2], Blr[2];
    #pragma unroll
    for (int s = 0; s < 8; ++s) {
        const size_t o = (size_t)(rw0 + 32*s)*CH + cq*4;
        Ahr[s] = *(const v4s*)&wph2[o];
        Alr[s] = *(const v4s*)&wpl2[o];
    }
    #pragma unroll
    for (int s = 0; s < 2; ++s) {
        const size_t o = (size_t)(rw0 + 32*s)*CH + cq*4;
        Bhr[s] = *(const v4s*)&pbh[o];
        Blr[s] = *(const v4s*)&pbl[o];
    }

    v4f acc[4][4];
    #pragma unroll
    for (int a = 0; a < 4; ++a)
        #pragma unroll
        for (int c = 0; c < 4; ++c) acc[a][c] = (v4f){0.f,0.f,0.f,0.f};

    for (int it = 0; it < 24; ++it) {
        __syncthreads();
        #pragma unroll
        for (int s = 0; s < 8; ++s) {
            const int cl = rw0 + 32*s;
            *(v4s*)&Awh[cl*40 + cq*4] = Ahr[s];
            *(v4s*)&Awl[cl*40 + cq*4] = Alr[s];
        }
        #pragma unroll
        for (int s = 0; s < 2; ++s) {
            const int nl = rw0 + 32*s;
            *(v4s*)&Bph[nl*40 + cq*4] = Bhr[s];
            *(v4s*)&Bpl[nl*40 + cq*4] = Blr[s];
        }
        __syncthreads();
        if (it < 23) {
            const int k0g = (it + 1) * 32;
            #pragma unroll
            for (int s = 0; s < 8; ++s) {
                const size_t o = (size_t)(rw0 + 32*s)*CH + k0g + cq*4;
                Ahr[s] = *(const v4s*)&wph2[o];
                Alr[s] = *(const v4s*)&wpl2[o];
            }
            #pragma unroll
            for (int s = 0; s < 2; ++s) {
                const size_t o = (size_t)(rw0 + 32*s)*CH + k0g + cq*4;
                Bhr[s] = *(const v4s*)&pbh[o];
                Blr[s] = *(const v4s*)&pbl[o];
            }
        }
        const int krow = lane & 15;
        const int k0   = (lane >> 4) * 8;
        v8s ah[4], al2[4], bh[4], bl[4];
        #pragma unroll
        for (int mt = 0; mt < 4; ++mt) {
            ah[mt]  = *(v8s*)&Awh[(wv*64 + mt*16 + krow)*40 + k0];
            al2[mt] = *(v8s*)&Awl[(wv*64 + mt*16 + krow)*40 + k0];
        }
        #pragma unroll
        for (int jt = 0; jt < 4; ++jt) {
            bh[jt] = *(v8s*)&Bph[(jt*16 + krow)*40 + k0];
            bl[jt] = *(v8s*)&Bpl[(jt*16 + krow)*40 + k0];
        }
        #pragma unroll
        for (int mt = 0; mt < 4; ++mt)
            #pragma unroll
            for (int jt = 0; jt < 4; ++jt) {
                acc[mt][jt] = __builtin_amdgcn_mfma_f32_16x16x32_bf16(ah[mt],  bh[jt], acc[mt][jt], 0, 0, 0);
                acc[mt][jt] = __builtin_amdgcn_mfma_f32_16x16x32_bf16(ah[mt],  bl[jt], acc[mt][jt], 0, 0, 0);
                acc[mt][jt] = __builtin_amdgcn_mfma_f32_16x16x32_bf16(al2[mt], bh[jt], acc[mt][jt], 0, 0, 0);
            }
    }

    const int col  = lane & 15;
    const int row4 = (lane >> 4) * 4;
    #pragma unroll
    for (int mt = 0; mt < 4; ++mt)
        #pragma unroll
        for (int rg = 0; rg < 4; ++rg) {
            const int co = co0 + wv*64 + mt*16 + row4 + rg;
            const float bi = bias[co];
            #pragma unroll
            for (int jt = 0; jt < 4; ++jt)
                out[((size_t)b * CH + co) * NTOK + nn0 + jt*16 + col] =
                    acc[mt][jt][rg] + bi;
        }
}

// ---------------------------------------------------------------------------
extern "C" void kernel_launch(void* const* d_in, const int* in_sizes, int n_in,
                              void* d_out, int out_size, void* d_ws, size_t ws_size,
                              hipStream_t stream)
{
    (void)in_sizes; (void)n_in; (void)out_size; (void)ws_size;
    const float* x     = (const float*)d_in[0];
    const float* wqkv  = (const float*)d_in[1];
    const float* wproj = (const float*)d_in[2];
    const float* bproj = (const float*)d_in[3];
    float* out = (float*)d_out;

    float* vbuf = (float*)d_ws;                               // NELEM f32
    short* xh   = (short*)(vbuf + NELEM);                     // NELEM bf16
    short* xl   = xh + NELEM;
    short* wqh  = xl + NELEM;                                 // 2304*768
    short* wql  = wqh + 2304*768;
    short* wph  = wql + 2304*768;                             // 768*768
    short* wpl  = wph + 768*768;
    unsigned char* vt8 = (unsigned char*)(wpl + 768*768);     // 192*36864 B
    unsigned long long* qmask =
        (unsigned long long*)(vt8 + (size_t)B_*NH*VT8SZ);
    unsigned long long* kmask = qmask + (B_*NH*NTOK);
    float* cs     = (float*)(kmask + (B_*NH*NTOK));           // 192
    int*   csum_p = (int*)(cs + B_*NH);                       // 192*4*64
    float* scale  = (float*)(csum_p + B_*NH*4*HD);            // 192*64
    float* svs_g  = scale + B_*NH*HD;                         // 192*64
    float* sumq_p = svs_g + B_*NH*HD;                         // 192*9
    float* sumk_p = sumq_p + B_*NH*9;
    float* vmax_p = sumk_p + B_*NH*9;                         // 192*9*64
    int*   fixq_g = (int*)(vmax_p + B_*NH*9*HD);              // FIXCAP
    int*   fixn_g = fixq_g + FIXCAP;
    short* preh = xh;   // xh/xl dead after qkv_mfma -> recycle for pre
    short* prel = xl;

    splitx<<<dim3(9, 12, B_), 256, 0, stream>>>(x, xh, xl, fixn_g);
    splitw<<<dim3(576), 256, 0, stream>>>(wqkv, wproj, wqh, wql, wph, wpl);
    qkv_mfma<<<dim3(1296), 256, 0, stream>>>(xh, xl, wqh, wql, vbuf,
        qmask, kmask, sumq_p, sumk_p, vmax_p, fixq_g, fixn_g);
    finalize<<<dim3(B_*NH), 64, 0, stream>>>(sumq_p, sumk_p, vmax_p,
        cs, svs_g, scale);
    vquant<<<dim3(B_*NH, 4), 256, 0, stream>>>(vbuf, svs_g, vt8, csum_p);
    fixup<<<dim3(64), 256, 0, stream>>>(x, wqkv, qmask, kmask, fixq_g, fixn_g);
    attn_i8<<<dim3(9, NH, B_), 256, 0, stream>>>(qmask, kmask, vt8, cs,
                                                 csum_p, scale, preh, prel);
    proj_mfma<<<dim3(432), 256, 0, stream>>>(preh, prel, wph, wpl, bproj, out);
}